// Round 3
// baseline (409.612 us; speedup 1.0000x reference)
//
#include <hip/hip_runtime.h>
#include <stdint.h>

#define N_SAMP 131072
#define DIN    256
#define HIDN   1024
#define RW     64            // rows per wave (= per block); 2048 blocks
#define NCT    (HIDN / 16)   // 64 col-tiles

typedef __attribute__((ext_vector_type(8))) short short8;
typedef __attribute__((ext_vector_type(4))) float f32x4;

__device__ __forceinline__ unsigned short f2bf(float f) {
  unsigned u = __float_as_uint(f);
  u += 0x7fffu + ((u >> 16) & 1u);   // round-to-nearest-even (inputs finite)
  return (unsigned short)(u >> 16);
}

__device__ __forceinline__ short8 pack8(float4 a, float4 b) {
  short8 r;
  r[0] = (short)f2bf(a.x); r[1] = (short)f2bf(a.y);
  r[2] = (short)f2bf(a.z); r[3] = (short)f2bf(a.w);
  r[4] = (short)f2bf(b.x); r[5] = (short)f2bf(b.y);
  r[6] = (short)f2bf(b.z); r[7] = (short)f2bf(b.w);
  return r;
}

// Pre-convert W1 (fp32 [1024][256]) -> bf16 row-major in workspace (512 KB).
__global__ __launch_bounds__(256) void w1_to_bf16(const float* __restrict__ W1,
                                                  unsigned short* __restrict__ o) {
  int i = blockIdx.x * 256 + threadIdx.x;          // 65536 threads, 4 elems each
  float4 f = ((const float4*)W1)[i];
  ushort4 v;
  v.x = f2bf(f.x); v.y = f2bf(f.y); v.z = f2bf(f.z); v.w = f2bf(f.w);
  ((ushort4*)o)[i] = v;
}

// Fused: h = relu(x@W1^T + b1); y = dot(We[c[num]], h) + be[...]; out = sigmoid(y)
// One wave per block, 64 rows per wave, no LDS, no barriers.
// A (x rows, bf16) register-resident for full K=256; B (W1) streamed from L2.
template <bool WBF>
__global__ __launch_bounds__(64, 2) void fused_kernel(
    const float* __restrict__ x,
    const float* __restrict__ W1f,
    const unsigned short* __restrict__ W1b,
    const float* __restrict__ b1,
    const float* __restrict__ We,   // [100][1024]
    const float* __restrict__ be,   // [100]
    const int* __restrict__ num,    // [N]
    const int* __restrict__ c,      // [100]
    float* __restrict__ out)        // [N]
{
  const int lane = threadIdx.x;     // 0..63
  const int m    = lane & 15;       // MFMA n/col lane coord
  const int quad = lane >> 4;       // 0..3
  const int R0   = blockIdx.x * RW;

  // ---- expert row offsets for my 16 (t,r) rows: row = t*16 + quad*4 + r
  int eoff[4][4];
#pragma unroll
  for (int t = 0; t < 4; ++t)
#pragma unroll
    for (int r = 0; r < 4; ++r)
      eoff[t][r] = c[num[R0 + t * 16 + quad * 4 + r]] * HIDN;

  // ---- A fragments: 4 row-tiles x 8 k-steps, register-resident (128 VGPRs).
  // A[m=lane&15][k=quad*8+j]; k0 = s*32 + quad*8.
  short8 afr[4][8];
  {
    const float* xr0 = x + (size_t)(R0 + m) * DIN + quad * 8;
#pragma unroll
    for (int t = 0; t < 4; ++t) {
      const float* xr = xr0 + (size_t)t * 16 * DIN;
#pragma unroll
      for (int s = 0; s < 8; ++s) {
        float4 f0 = *(const float4*)(xr + s * 32);
        float4 f1 = *(const float4*)(xr + s * 32 + 4);
        afr[t][s] = pack8(f0, f1);
      }
    }
  }

  float yacc[4][4];
#pragma unroll
  for (int t = 0; t < 4; ++t)
#pragma unroll
    for (int r = 0; r < 4; ++r) yacc[t][r] = 0.f;

  // ---- sweep 64 col-tiles of 16 hidden units
  for (int ct = 0; ct < NCT; ++ct) {
    // B fragments for this col-tile: B[n=lane&15][k=quad*8+j], 8 k-steps.
    short8 bfr[8];
    if (WBF) {
      const unsigned short* wb = W1b + (size_t)(ct * 16 + m) * DIN + quad * 8;
#pragma unroll
      for (int s = 0; s < 8; ++s)
        bfr[s] = *(const short8*)(wb + s * 32);
    } else {
      const float* wf = W1f + (size_t)(ct * 16 + m) * DIN + quad * 8;
#pragma unroll
      for (int s = 0; s < 8; ++s) {
        float4 f0 = *(const float4*)(wf + s * 32);
        float4 f1 = *(const float4*)(wf + s * 32 + 4);
        bfr[s] = pack8(f0, f1);
      }
    }

    f32x4 acc[4];
#pragma unroll
    for (int t = 0; t < 4; ++t) acc[t] = (f32x4){0.f, 0.f, 0.f, 0.f};

#pragma unroll
    for (int s = 0; s < 8; ++s)
#pragma unroll
      for (int t = 0; t < 4; ++t)
        acc[t] = __builtin_amdgcn_mfma_f32_16x16x32_bf16(
            afr[t][s], bfr[s], acc[t], 0, 0, 0);

    // ---- epilogue: +b1, relu, * gathered We row, accumulate per-row y
    // C layout: col(n) = lane&15, row(m-dim) = quad*4 + reg  [m89/m91]
    const int col = ct * 16 + m;
    const float bv = b1[col];
    const float* Wec = We + col;
#pragma unroll
    for (int t = 0; t < 4; ++t)
#pragma unroll
      for (int r = 0; r < 4; ++r) {
        float h = acc[t][r] + bv;
        h = fmaxf(h, 0.f);
        yacc[t][r] = fmaf(h, Wec[eoff[t][r]], yacc[t][r]);
      }
  }

  // ---- reduce partial y across the 16 n-lanes of each quad group
#pragma unroll
  for (int t = 0; t < 4; ++t)
#pragma unroll
    for (int r = 0; r < 4; ++r) {
      float v = yacc[t][r];
      v += __shfl_xor(v, 1);
      v += __shfl_xor(v, 2);
      v += __shfl_xor(v, 4);
      v += __shfl_xor(v, 8);
      yacc[t][r] = v;
    }

  if (m == 0) {
#pragma unroll
    for (int t = 0; t < 4; ++t)
#pragma unroll
      for (int r = 0; r < 4; ++r) {
        int row = R0 + t * 16 + quad * 4 + r;
        float yy = yacc[t][r] + be[eoff[t][r] >> 10];  // eoff/HIDN
        out[row] = 1.f / (1.f + __expf(-yy));
      }
  }
}

extern "C" void kernel_launch(void* const* d_in, const int* in_sizes, int n_in,
                              void* d_out, int out_size, void* d_ws, size_t ws_size,
                              hipStream_t stream) {
  const float* x   = (const float*)d_in[0];
  const float* W1  = (const float*)d_in[1];
  const float* b1  = (const float*)d_in[2];
  const float* We  = (const float*)d_in[3];
  const float* be  = (const float*)d_in[4];
  const int*   num = (const int*)d_in[5];
  const int*   c   = (const int*)d_in[6];
  float* out = (float*)d_out;

  const size_t w1bf_bytes = (size_t)HIDN * DIN * sizeof(unsigned short);
  const bool usebf = ws_size >= w1bf_bytes;
  unsigned short* w1bf = (unsigned short*)d_ws;

  if (usebf) {
    w1_to_bf16<<<dim3((HIDN * DIN / 4) / 256), dim3(256), 0, stream>>>(W1, w1bf);
    fused_kernel<true><<<dim3(N_SAMP / RW), dim3(64), 0, stream>>>(
        x, W1, w1bf, b1, We, be, num, c, out);
  } else {
    fused_kernel<false><<<dim3(N_SAMP / RW), dim3(64), 0, stream>>>(
        x, W1, w1bf, b1, We, be, num, c, out);
  }
}

// Round 4
// 260.927 us; speedup vs baseline: 1.5698x; 1.5698x over previous
//
#include <hip/hip_runtime.h>
#include <stdint.h>

#define N_SAMP 131072
#define DIN    256
#define HIDN   1024
#define BROWS  128           // rows per block, 32 per wave; 1024 blocks
#define NCHUNK 16            // 16 chunks of 64 hidden cols

typedef __attribute__((ext_vector_type(8))) short short8;
typedef __attribute__((ext_vector_type(4))) float f32x4;

__device__ __forceinline__ unsigned short f2bf(float f) {
  unsigned u = __float_as_uint(f);
  u += 0x7fffu + ((u >> 16) & 1u);   // round-to-nearest-even (inputs finite)
  return (unsigned short)(u >> 16);
}

__device__ __forceinline__ short8 pack8(float4 a, float4 b) {
  short8 r;
  r[0] = (short)f2bf(a.x); r[1] = (short)f2bf(a.y);
  r[2] = (short)f2bf(a.z); r[3] = (short)f2bf(a.w);
  r[4] = (short)f2bf(b.x); r[5] = (short)f2bf(b.y);
  r[6] = (short)f2bf(b.z); r[7] = (short)f2bf(b.w);
  return r;
}

// Pre-convert W1 (fp32 [1024][256]) -> bf16 row-major in workspace (512 KB).
__global__ __launch_bounds__(256) void w1_to_bf16(const float* __restrict__ W1,
                                                  unsigned short* __restrict__ o) {
  int i = blockIdx.x * 256 + threadIdx.x;          // 65536 threads, 4 elems each
  float4 f = ((const float4*)W1)[i];
  ushort4 v;
  v.x = f2bf(f.x); v.y = f2bf(f.y); v.z = f2bf(f.z); v.w = f2bf(f.w);
  ((ushort4*)o)[i] = v;
}

// Fused: h = relu(x@W1^T + b1); y = dot(We[c[num]], h) + be[...]; out = sigmoid(y)
// 4 waves/block, 32 rows/wave (afr = 64 VGPRs, stays in arch regs — no spill).
// W1(bf16) double-buffer staged to LDS via global_load_lds (zero staging regs).
// LDS swizzle: 16B-group kg of row r stored at phys kg ^ ((r&7)<<2)  → B-frag
// reads are 2-way bank aliased (free, m136); staging spans stay contiguous.
template <bool WBF>
__global__ __launch_bounds__(256, 2) void fused_kernel(
    const float* __restrict__ x,
    const float* __restrict__ W1f,
    const unsigned short* __restrict__ W1b,
    const float* __restrict__ b1,
    const float* __restrict__ We,   // [100][1024]
    const float* __restrict__ be,   // [100]
    const int* __restrict__ num,    // [N]
    const int* __restrict__ c,      // [100]
    float* __restrict__ out)        // [N]
{
  __shared__ unsigned short Wt[2][64 * DIN];  // 2 x 32 KB
  __shared__ int e_sh[BROWS];

  const int tid  = threadIdx.x;
  const int lane = tid & 63;
  const int w    = tid >> 6;        // wave 0..3
  const int n    = lane & 15;       // MFMA m/n lane coord
  const int quad = lane >> 4;       // 0..3
  const int R0   = blockIdx.x * BROWS;

  if (tid < BROWS) e_sh[tid] = c[num[R0 + tid]];

  // ---- A fragments: 2 row-tiles x 8 k-steps, register-resident (64 VGPRs).
  // A[m=lane&15][k=quad*8+j]; k0 = s*32 + quad*8.
  short8 afr[2][8];
  {
    const float* xr0 = x + (size_t)(R0 + w * 32 + n) * DIN + quad * 8;
#pragma unroll
    for (int t = 0; t < 2; ++t) {
      const float* xr = xr0 + (size_t)t * 16 * DIN;
#pragma unroll
      for (int s = 0; s < 8; ++s) {
        float4 f0 = *(const float4*)(xr + s * 32);
        float4 f1 = *(const float4*)(xr + s * 32 + 4);
        afr[t][s] = pack8(f0, f1);
      }
    }
  }

  const int h2 = lane >> 5;   // staging: row-within-pair
  const int p  = lane & 31;   // staging: physical 16B slot in row

  // ---- stage chunk 0 into buf 0
  if (WBF) {
#pragma unroll
    for (int j = 0; j < 8; ++j) {
      int inst = w * 8 + j;
      int r = inst * 2 + h2;
      int kg = p ^ ((r & 7) << 2);
      const unsigned short* g = W1b + (r << 8) + (kg << 3);
      __builtin_amdgcn_global_load_lds(
          (const __attribute__((address_space(1))) unsigned int*)g,
          (__attribute__((address_space(3))) unsigned int*)(&Wt[0][0] + inst * 512),
          16, 0, 0);
    }
  } else {
#pragma unroll
    for (int j = 0; j < 8; ++j) {
      int id = tid + j * 256;
      int r = id >> 5, pp = id & 31;
      int kg = pp ^ ((r & 7) << 2);
      const float* gs = W1f + (r << 8) + (kg << 3);
      float4 f0 = *(const float4*)gs;
      float4 f1 = *(const float4*)(gs + 4);
      *(short8*)&Wt[0][r * DIN + pp * 8] = pack8(f0, f1);
    }
  }

  __syncthreads();  // e_sh + chunk 0 ready

  int eoff[2][4];
#pragma unroll
  for (int t = 0; t < 2; ++t)
#pragma unroll
    for (int r = 0; r < 4; ++r)
      eoff[t][r] = e_sh[w * 32 + t * 16 + quad * 4 + r] * HIDN;

  float yacc[2][4] = {{0.f, 0.f, 0.f, 0.f}, {0.f, 0.f, 0.f, 0.f}};

  int buf = 0;
  for (int ch = 0; ch < NCHUNK; ++ch) {
    // ---- async-stage next chunk into the other buffer (lands during compute)
    if (ch + 1 < NCHUNK) {
      if (WBF) {
        const unsigned short* Wg = W1b + (size_t)(ch + 1) * (64 * DIN);
        unsigned short* db = &Wt[buf ^ 1][0];
#pragma unroll
        for (int j = 0; j < 8; ++j) {
          int inst = w * 8 + j;
          int r = inst * 2 + h2;
          int kg = p ^ ((r & 7) << 2);
          const unsigned short* g = Wg + (r << 8) + (kg << 3);
          __builtin_amdgcn_global_load_lds(
              (const __attribute__((address_space(1))) unsigned int*)g,
              (__attribute__((address_space(3))) unsigned int*)(db + inst * 512),
              16, 0, 0);
        }
      } else {
        const float* Wg = W1f + (size_t)(ch + 1) * (64 * DIN);
#pragma unroll
        for (int j = 0; j < 8; ++j) {
          int id = tid + j * 256;
          int r = id >> 5, pp = id & 31;
          int kg = pp ^ ((r & 7) << 2);
          const float* gs = Wg + (r << 8) + (kg << 3);
          float4 f0 = *(const float4*)gs;
          float4 f1 = *(const float4*)(gs + 4);
          *(short8*)&Wt[buf ^ 1][r * DIN + pp * 8] = pack8(f0, f1);
        }
      }
    }

    // ---- MFMA over this chunk: 2 row-tiles x 4 col-tiles, K=256
    const unsigned short* WtB = &Wt[buf][0];
    f32x4 acc[2][4];
#pragma unroll
    for (int t = 0; t < 2; ++t)
#pragma unroll
      for (int nt = 0; nt < 4; ++nt)
        acc[t][nt] = (f32x4){0.f, 0.f, 0.f, 0.f};

#pragma unroll
    for (int s = 0; s < 8; ++s) {
      const int F = (s * 4 + quad) ^ ((n & 7) << 2);  // swizzled 16B slot
      short8 bfr[4];
#pragma unroll
      for (int nt = 0; nt < 4; ++nt)
        bfr[nt] = *(const short8*)&WtB[(nt * 16 + n) * DIN + F * 8];
#pragma unroll
      for (int t = 0; t < 2; ++t)
#pragma unroll
        for (int nt = 0; nt < 4; ++nt)
          acc[t][nt] = __builtin_amdgcn_mfma_f32_16x16x32_bf16(
              afr[t][s], bfr[nt], acc[t][nt], 0, 0, 0);
    }

    // ---- epilogue: +b1, relu, * gathered We row, accumulate y
    // C layout: col(n) = lane&15, row = quad*4 + reg  [m89/m91]
#pragma unroll
    for (int nt = 0; nt < 4; ++nt) {
      int col = ch * 64 + nt * 16 + n;
      float bv = b1[col];
      const float* Wec = We + col;
#pragma unroll
      for (int t = 0; t < 2; ++t)
#pragma unroll
        for (int r = 0; r < 4; ++r) {
          float h = acc[t][nt][r] + bv;
          h = fmaxf(h, 0.f);
          yacc[t][r] = fmaf(h, Wec[eoff[t][r]], yacc[t][r]);
        }
    }

    __syncthreads();  // all reads of buf done; next-chunk staging drained
    buf ^= 1;
  }

  // ---- reduce partial y across the 16 n-lanes of each quad group
#pragma unroll
  for (int t = 0; t < 2; ++t)
#pragma unroll
    for (int r = 0; r < 4; ++r) {
      float v = yacc[t][r];
      v += __shfl_xor(v, 1);
      v += __shfl_xor(v, 2);
      v += __shfl_xor(v, 4);
      v += __shfl_xor(v, 8);
      yacc[t][r] = v;
    }

  if (n == 0) {
#pragma unroll
    for (int t = 0; t < 2; ++t)
#pragma unroll
      for (int r = 0; r < 4; ++r) {
        int row = R0 + w * 32 + t * 16 + quad * 4 + r;
        float yy = yacc[t][r] + be[eoff[t][r] >> 10];  // eoff / HIDN
        out[row] = 1.f / (1.f + __expf(-yy));
      }
  }
}

extern "C" void kernel_launch(void* const* d_in, const int* in_sizes, int n_in,
                              void* d_out, int out_size, void* d_ws, size_t ws_size,
                              hipStream_t stream) {
  const float* x   = (const float*)d_in[0];
  const float* W1  = (const float*)d_in[1];
  const float* b1  = (const float*)d_in[2];
  const float* We  = (const float*)d_in[3];
  const float* be  = (const float*)d_in[4];
  const int*   num = (const int*)d_in[5];
  const int*   c   = (const int*)d_in[6];
  float* out = (float*)d_out;

  const size_t w1bf_bytes = (size_t)HIDN * DIN * sizeof(unsigned short);
  const bool usebf = ws_size >= w1bf_bytes;
  unsigned short* w1bf = (unsigned short*)d_ws;

  if (usebf) {
    w1_to_bf16<<<dim3((HIDN * DIN / 4) / 256), dim3(256), 0, stream>>>(W1, w1bf);
    fused_kernel<true><<<dim3(N_SAMP / BROWS), dim3(256), 0, stream>>>(
        x, W1, w1bf, b1, We, be, num, c, out);
  } else {
    fused_kernel<false><<<dim3(N_SAMP / BROWS), dim3(256), 0, stream>>>(
        x, W1, w1bf, b1, We, be, num, c, out);
  }
}